// Round 11
// baseline (50.646 us; speedup 1.0000x reference)
//
#include <hip/hip_runtime.h>

#define NB 8
#define TE 256
#define TD 256
#define ED 512
#define DU 256

// EpeT2 layout: [b][uq=u/4][t][ui=u%4]  (64 x 256 x 4 floats per b = 65536)

// K1: proj+exp, 32x64 tiles, 512 threads (8 waves): K-split (R5 form,
// best measured). 2 blocks/CU x 8 waves = 4 waves/SIMD.
__global__ __launch_bounds__(512) void proj_exp_kernel(
    const float* __restrict__ enc, const float* __restrict__ dec,
    const float* __restrict__ W1, const float* __restrict__ b1,
    const float* __restrict__ W2, const float* __restrict__ b2,
    float* __restrict__ Epd, float* __restrict__ EpeT2)
{
  __shared__ __align__(16) float As[2][32][34];
  __shared__ __align__(16) float Bs[2][32][64];
  __shared__ __align__(16) float comb[8][256];
  const int blk = blockIdx.x;
  const bool is_pe = blk < 256;
  const int sub = blk & 255;
  const int K = is_pe ? ED : DU;
  const int NTh = K >> 6;  // K-tiles per half (pe: 8, pd: 4)
  const float* __restrict__ A = is_pe ? enc : dec;
  const float* __restrict__ W = is_pe ? W1 : W2;
  const float* __restrict__ bias = is_pe ? b1 : b2;
  const int mt = sub >> 2, nt = sub & 3;
  const int m0 = mt * 32, n0 = nt * 64;
  const int tid = threadIdx.x;
  const int t = tid & 255;  // index within half
  const int h = tid >> 8;   // K-half
  const int k0base = h * (K >> 1);
  const int tx = t & 15, ty = t >> 4;
  const int at = t >> 3, ka = (t & 7) << 2;   // A: row, k-offset
  const int kb = t >> 4, jb = (t & 15) << 2;  // W: k-row, col-offset

  const float* __restrict__ Ap = A + (size_t)(m0 + at) * K + k0base + ka;
  const float* __restrict__ Wp = W + (size_t)(k0base + kb) * DU + n0 + jb;

  float acc[2][4] = {};
  float4 aV, wV0, wV1;

  auto loadr = [&](int k0) {
    aV = *(const float4*)(Ap + k0);
    wV0 = *(const float4*)(Wp + (size_t)k0 * DU);
    wV1 = *(const float4*)(Wp + (size_t)(k0 + 16) * DU);
  };

  loadr(0);
  for (int kt = 0; kt < NTh; ++kt) {
    As[h][ka + 0][at] = aV.x;
    As[h][ka + 1][at] = aV.y;
    As[h][ka + 2][at] = aV.z;
    As[h][ka + 3][at] = aV.w;
    *(float4*)&Bs[h][kb][jb] = wV0;
    *(float4*)&Bs[h][kb + 16][jb] = wV1;
    __syncthreads();
    if (kt + 1 < NTh) loadr((kt + 1) << 5);
#pragma unroll
    for (int kk = 0; kk < 32; ++kk) {
      const float2 a2 = *(const float2*)&As[h][kk][ty * 2];
      const float4 w4 = *(const float4*)&Bs[h][kk][tx * 4];
      acc[0][0] = fmaf(a2.x, w4.x, acc[0][0]);
      acc[0][1] = fmaf(a2.x, w4.y, acc[0][1]);
      acc[0][2] = fmaf(a2.x, w4.z, acc[0][2]);
      acc[0][3] = fmaf(a2.x, w4.w, acc[0][3]);
      acc[1][0] = fmaf(a2.y, w4.x, acc[1][0]);
      acc[1][1] = fmaf(a2.y, w4.y, acc[1][1]);
      acc[1][2] = fmaf(a2.y, w4.z, acc[1][2]);
      acc[1][3] = fmaf(a2.y, w4.w, acc[1][3]);
    }
    __syncthreads();
  }

  // ---- combine K-halves ----
  if (h == 1) {
#pragma unroll
    for (int r = 0; r < 2; ++r)
#pragma unroll
      for (int j = 0; j < 4; ++j) comb[r * 4 + j][t] = acc[r][j];
  }
  __syncthreads();
  if (h == 0) {
#pragma unroll
    for (int r = 0; r < 2; ++r)
#pragma unroll
      for (int j = 0; j < 4; ++j) acc[r][j] += comb[r * 4 + j][t];

    const float4 bv4 = *(const float4*)(bias + n0 + tx * 4);
    const float bvv[4] = {bv4.x, bv4.y, bv4.z, bv4.w};
    if (is_pe) {
      const int b = m0 >> 8, t0 = m0 & 255;
      const int uqg = (b << 6) + (n0 >> 2) + tx;
      const int tg = t0 + ty * 2;
      float* dst = EpeT2 + ((size_t)uqg << 10) + (tg << 2);
      float4 o0, o1;
      o0.x = __expf(2.0f * (acc[0][0] + bvv[0]));
      o0.y = __expf(2.0f * (acc[0][1] + bvv[1]));
      o0.z = __expf(2.0f * (acc[0][2] + bvv[2]));
      o0.w = __expf(2.0f * (acc[0][3] + bvv[3]));
      o1.x = __expf(2.0f * (acc[1][0] + bvv[0]));
      o1.y = __expf(2.0f * (acc[1][1] + bvv[1]));
      o1.z = __expf(2.0f * (acc[1][2] + bvv[2]));
      o1.w = __expf(2.0f * (acc[1][3] + bvv[3]));
      *(float4*)dst = o0;
      *(float4*)(dst + 4) = o1;
    } else {
#pragma unroll
      for (int r = 0; r < 2; ++r) {
        const int m = m0 + ty * 2 + r;
        float4 o;
        o.x = __expf(2.0f * (acc[r][0] + bvv[0]));
        o.y = __expf(2.0f * (acc[r][1] + bvv[1]));
        o.z = __expf(2.0f * (acc[r][2] + bvv[2]));
        o.w = __expf(2.0f * (acc[r][3] + bvv[3]));
        *(float4*)(Epd + ((size_t)m << 8) + n0 + tx * 4) = o;
      }
    }
  }
}

// K23: fused score+softmax+context, 512 threads (8 waves), grid 512 =
// (b, s-quad), XCD swizzle. Structure = R10 (best: 47.5us).
// Phase 1 SINGLE LEVER vs R10: quad-denominator combine — one rcp per
// u-quad instead of four:
//   vwx/A+vwy/B+vwz/C+vww/D = (p1*CD + p2*AB)/(AB*CD),
//   p1 = vwx*B+vwy*A, p2 = vwz*D+vww*C.
// 14 VALU + 1 rcp per quad (was 8 VALU + 4 rcp). Tests the trans-pipe
// issue model: if rcp blocks issue ~8cyc, phase-1 issue drops 25%.
// Numerics: A..D in [1,~1e7] for N(0,1) projections -> AB*CD <= ~1e28,
// well inside fp32; rcp >= 1e-28 >> denormal floor.
// Softmax: no-max (validated R6-R10). Phase 2 unchanged from R9/R10.
__global__ __launch_bounds__(512) void score_ctx_kernel(
    const float* __restrict__ Epd, const float* __restrict__ EpeT2,
    const float* __restrict__ Vw, const float* __restrict__ enc,
    float* __restrict__ attn, float* __restrict__ ctx)
{
  __shared__ __align__(16) float eps[4 * 256];     // Epd rows (4KB)
  __shared__ __align__(16) float vws[256];         // Vw (1KB)
  __shared__ __align__(16) float comb[4][4][256];  // u-quarter partials (16KB)
  __shared__ __align__(16) float att[4][256];      // probs (4KB)
  __shared__ __align__(16) float ctx2[3][4][512];  // t-quarter partials (24KB)
  __shared__ float reds[4][4];

  const int blk0 = blockIdx.x;
  const int blk = ((blk0 & 7) << 6) | (blk0 >> 3);  // T1 XCD swizzle
  const int b = blk >> 6;
  const int s0 = (blk & 63) << 2;
  const int tid = threadIdx.x;

  // ---- stage Epd 4 rows (contiguous 4KB) + Vw (1KB) into LDS ----
  if (tid < 256) {
    ((float4*)eps)[tid] =
        ((const float4*)(Epd + (((size_t)((b << 8) + s0)) << 8)))[tid];
  } else if (tid < 320) {
    ((float4*)vws)[tid - 256] = ((const float4*)Vw)[tid - 256];
  }
  __syncthreads();

  // ---- Phase 1: u-quarter hq, t-pair {p, p+128} ----
  const int p = tid & 127;
  const int hq = tid >> 7;  // 0..3 (wave-uniform: 2 waves per quarter)
  const int qb = hq << 4;   // 16 q per quarter
  const float* __restrict__ epA =
      EpeT2 + ((size_t)b << 16) + ((size_t)qb << 10) + (p << 2);
  const float* __restrict__ epB = epA + (128 << 2);

  float accA[4] = {};  // rows, t = p
  float accB[4] = {};  // rows, t = p+128
  float4 ga = *(const float4*)epA;
  float4 gb = *(const float4*)epB;
#pragma unroll 4
  for (int q = 0; q < 16; ++q) {
    float4 gan, gbn;
    if (q + 1 < 16) {
      gan = *(const float4*)(epA + ((size_t)(q + 1) << 10));
      gbn = *(const float4*)(epB + ((size_t)(q + 1) << 10));
    }
    const int u4 = (qb + q) << 2;
    const float4 vw = *(const float4*)&vws[u4];
    const float4 er[4] = {*(const float4*)&eps[u4],
                          *(const float4*)&eps[256 + u4],
                          *(const float4*)&eps[512 + u4],
                          *(const float4*)&eps[768 + u4]};
#pragma unroll
    for (int r = 0; r < 4; ++r) {
      const float4 e = er[r];
      {  // t = p
        const float A = fmaf(e.x, ga.x, 1.0f);
        const float B = fmaf(e.y, ga.y, 1.0f);
        const float C = fmaf(e.z, ga.z, 1.0f);
        const float D = fmaf(e.w, ga.w, 1.0f);
        const float AB = A * B, CD = C * D;
        const float p1 = fmaf(vw.y, A, vw.x * B);
        const float p2 = fmaf(vw.w, C, vw.z * D);
        const float num = fmaf(p2, AB, p1 * CD);
        accA[r] = fmaf(num, __builtin_amdgcn_rcpf(AB * CD), accA[r]);
      }
      {  // t = p+128
        const float A = fmaf(e.x, gb.x, 1.0f);
        const float B = fmaf(e.y, gb.y, 1.0f);
        const float C = fmaf(e.z, gb.z, 1.0f);
        const float D = fmaf(e.w, gb.w, 1.0f);
        const float AB = A * B, CD = C * D;
        const float p1 = fmaf(vw.y, A, vw.x * B);
        const float p2 = fmaf(vw.w, C, vw.z * D);
        const float num = fmaf(p2, AB, p1 * CD);
        accB[r] = fmaf(num, __builtin_amdgcn_rcpf(AB * CD), accB[r]);
      }
    }
    ga = gan;
    gb = gbn;
  }

#pragma unroll
  for (int r = 0; r < 4; ++r) {
    comb[hq][r][p] = accA[r];
    comb[hq][r][p + 128] = accB[r];
  }
  __syncthreads();

  // ---- combine quarters + no-max softmax on threads 0..255 ----
  const int wid = tid >> 6, lane = tid & 63;
  float e[4];
  if (tid < 256) {
    const int t = tid;
#pragma unroll
    for (int r = 0; r < 4; ++r) {
      const float v = (comb[0][r][t] + comb[1][r][t]) +
                      (comb[2][r][t] + comb[3][r][t]);
      e[r] = __expf(-2.f * v);
      float s = e[r];
#pragma unroll
      for (int off = 32; off; off >>= 1) s += __shfl_xor(s, off);
      if (lane == 0) reds[r][wid] = s;
    }
  }
  __syncthreads();
  if (tid < 256) {
    const int t = tid;
#pragma unroll
    for (int r = 0; r < 4; ++r) {
      const float s = (reds[r][0] + reds[r][1]) + (reds[r][2] + reds[r][3]);
      const float pr = e[r] * __builtin_amdgcn_rcpf(s);
      attn[(((size_t)((b << 8) + s0 + r)) << 8) + t] = pr;
      att[r][t] = pr;
    }
  }
  __syncthreads();

  // ---- Phase 2: thread owns cols c4..c4+3, rows s0..s0+3, t-quarter tq.
  const int c4 = (tid & 127) << 2;
  const int tq = tid >> 7;  // 0..3
  const int tb = tq << 6;   // 64 t per quarter
  const float* __restrict__ encb = enc + ((size_t)b << 17) + c4;
  float4 acc0 = {0.f, 0.f, 0.f, 0.f};
  float4 acc1 = {0.f, 0.f, 0.f, 0.f};
  float4 acc2 = {0.f, 0.f, 0.f, 0.f};
  float4 acc3 = {0.f, 0.f, 0.f, 0.f};
#pragma unroll 2
  for (int t0 = tb; t0 < tb + 64; t0 += 4) {
    const float4 p0 = *(const float4*)&att[0][t0];
    const float4 p1 = *(const float4*)&att[1][t0];
    const float4 p2 = *(const float4*)&att[2][t0];
    const float4 p3 = *(const float4*)&att[3][t0];
    const float pv0[4] = {p0.x, p0.y, p0.z, p0.w};
    const float pv1[4] = {p1.x, p1.y, p1.z, p1.w};
    const float pv2[4] = {p2.x, p2.y, p2.z, p2.w};
    const float pv3[4] = {p3.x, p3.y, p3.z, p3.w};
#pragma unroll
    for (int i = 0; i < 4; ++i) {
      const float4 ev = *(const float4*)(encb + ((size_t)(t0 + i) << 9));
      acc0.x = fmaf(pv0[i], ev.x, acc0.x);
      acc0.y = fmaf(pv0[i], ev.y, acc0.y);
      acc0.z = fmaf(pv0[i], ev.z, acc0.z);
      acc0.w = fmaf(pv0[i], ev.w, acc0.w);
      acc1.x = fmaf(pv1[i], ev.x, acc1.x);
      acc1.y = fmaf(pv1[i], ev.y, acc1.y);
      acc1.z = fmaf(pv1[i], ev.z, acc1.z);
      acc1.w = fmaf(pv1[i], ev.w, acc1.w);
      acc2.x = fmaf(pv2[i], ev.x, acc2.x);
      acc2.y = fmaf(pv2[i], ev.y, acc2.y);
      acc2.z = fmaf(pv2[i], ev.z, acc2.z);
      acc2.w = fmaf(pv2[i], ev.w, acc2.w);
      acc3.x = fmaf(pv3[i], ev.x, acc3.x);
      acc3.y = fmaf(pv3[i], ev.y, acc3.y);
      acc3.z = fmaf(pv3[i], ev.z, acc3.z);
      acc3.w = fmaf(pv3[i], ev.w, acc3.w);
    }
  }
  if (tq != 0) {
    *(float4*)&ctx2[tq - 1][0][c4] = acc0;
    *(float4*)&ctx2[tq - 1][1][c4] = acc1;
    *(float4*)&ctx2[tq - 1][2][c4] = acc2;
    *(float4*)&ctx2[tq - 1][3][c4] = acc3;
  }
  __syncthreads();
  if (tq == 0) {
#pragma unroll
    for (int q = 0; q < 3; ++q) {
      const float4 q0 = *(const float4*)&ctx2[q][0][c4];
      const float4 q1 = *(const float4*)&ctx2[q][1][c4];
      const float4 q2 = *(const float4*)&ctx2[q][2][c4];
      const float4 q3 = *(const float4*)&ctx2[q][3][c4];
      acc0.x += q0.x; acc0.y += q0.y; acc0.z += q0.z; acc0.w += q0.w;
      acc1.x += q1.x; acc1.y += q1.y; acc1.z += q1.z; acc1.w += q1.w;
      acc2.x += q2.x; acc2.y += q2.y; acc2.z += q2.z; acc2.w += q2.w;
      acc3.x += q3.x; acc3.y += q3.y; acc3.z += q3.z; acc3.w += q3.w;
    }
    float* __restrict__ cb = ctx + (((size_t)((b << 8) + s0)) << 9) + c4;
    *(float4*)(cb + 0 * ED) = acc0;
    *(float4*)(cb + 1 * ED) = acc1;
    *(float4*)(cb + 2 * ED) = acc2;
    *(float4*)(cb + 3 * ED) = acc3;
  }
}

extern "C" void kernel_launch(void* const* d_in, const int* in_sizes, int n_in,
                              void* d_out, int out_size, void* d_ws, size_t ws_size,
                              hipStream_t stream) {
  const float* enc = (const float*)d_in[0];
  const float* dec = (const float*)d_in[1];
  const float* W1 = (const float*)d_in[2];
  const float* b1 = (const float*)d_in[3];
  const float* W2 = (const float*)d_in[4];
  const float* b2 = (const float*)d_in[5];
  const float* Vw = (const float*)d_in[6];
  // Vb cancels in softmax — unused.

  float* ctx = (float*)d_out;                          // (8,256,512)
  float* attn = (float*)d_out + (size_t)NB * TD * ED;  // (8,256,256)
  float* Epd = (float*)d_ws;                           // 512K floats
  float* EpeT2 = Epd + (size_t)NB * TD * DU;           // 512K floats

  proj_exp_kernel<<<dim3(512), dim3(512), 0, stream>>>(enc, dec, W1, b1, W2,
                                                       b2, Epd, EpeT2);
  score_ctx_kernel<<<dim3(512), dim3(512), 0, stream>>>(Epd, EpeT2, Vw, enc,
                                                        attn, ctx);
}

// Round 12
// 48.433 us; speedup vs baseline: 1.0457x; 1.0457x over previous
//
#include <hip/hip_runtime.h>

#define NB 8
#define TE 256
#define TD 256
#define ED 512
#define DU 256

// EpeT2 layout: [b][uq=u/4][t][ui=u%4]  (64 x 256 x 4 floats per b = 65536)

// K1: proj+exp, 32x64 tiles, 512 threads (8 waves): K-split. Epilogue is
// now SYMMETRIC (R12): each K-half writes its partial for the row it does
// NOT own to LDS, reads the other half's partial for the row it DOES own
// (h0 -> row 0, h1 -> row 1), so all 512 threads do 4 exp + 1 store
// (was: h0 alone doing 8 exp + 2 stores).
__global__ __launch_bounds__(512) void proj_exp_kernel(
    const float* __restrict__ enc, const float* __restrict__ dec,
    const float* __restrict__ W1, const float* __restrict__ b1,
    const float* __restrict__ W2, const float* __restrict__ b2,
    float* __restrict__ Epd, float* __restrict__ EpeT2)
{
  __shared__ __align__(16) float As[2][32][34];
  __shared__ __align__(16) float Bs[2][32][64];
  __shared__ __align__(16) float combX[2][4][256];  // [h][j][t]: row (1-h)
  const int blk = blockIdx.x;
  const bool is_pe = blk < 256;
  const int sub = blk & 255;
  const int K = is_pe ? ED : DU;
  const int NTh = K >> 6;  // K-tiles per half (pe: 8, pd: 4)
  const float* __restrict__ A = is_pe ? enc : dec;
  const float* __restrict__ W = is_pe ? W1 : W2;
  const float* __restrict__ bias = is_pe ? b1 : b2;
  const int mt = sub >> 2, nt = sub & 3;
  const int m0 = mt * 32, n0 = nt * 64;
  const int tid = threadIdx.x;
  const int t = tid & 255;  // index within half
  const int h = tid >> 8;   // K-half
  const int k0base = h * (K >> 1);
  const int tx = t & 15, ty = t >> 4;
  const int at = t >> 3, ka = (t & 7) << 2;   // A: row, k-offset
  const int kb = t >> 4, jb = (t & 15) << 2;  // W: k-row, col-offset

  const float* __restrict__ Ap = A + (size_t)(m0 + at) * K + k0base + ka;
  const float* __restrict__ Wp = W + (size_t)(k0base + kb) * DU + n0 + jb;

  float acc[2][4] = {};
  float4 aV, wV0, wV1;

  auto loadr = [&](int k0) {
    aV = *(const float4*)(Ap + k0);
    wV0 = *(const float4*)(Wp + (size_t)k0 * DU);
    wV1 = *(const float4*)(Wp + (size_t)(k0 + 16) * DU);
  };

  loadr(0);
  for (int kt = 0; kt < NTh; ++kt) {
    As[h][ka + 0][at] = aV.x;
    As[h][ka + 1][at] = aV.y;
    As[h][ka + 2][at] = aV.z;
    As[h][ka + 3][at] = aV.w;
    *(float4*)&Bs[h][kb][jb] = wV0;
    *(float4*)&Bs[h][kb + 16][jb] = wV1;
    __syncthreads();
    if (kt + 1 < NTh) loadr((kt + 1) << 5);
#pragma unroll
    for (int kk = 0; kk < 32; ++kk) {
      const float2 a2 = *(const float2*)&As[h][kk][ty * 2];
      const float4 w4 = *(const float4*)&Bs[h][kk][tx * 4];
      acc[0][0] = fmaf(a2.x, w4.x, acc[0][0]);
      acc[0][1] = fmaf(a2.x, w4.y, acc[0][1]);
      acc[0][2] = fmaf(a2.x, w4.z, acc[0][2]);
      acc[0][3] = fmaf(a2.x, w4.w, acc[0][3]);
      acc[1][0] = fmaf(a2.y, w4.x, acc[1][0]);
      acc[1][1] = fmaf(a2.y, w4.y, acc[1][1]);
      acc[1][2] = fmaf(a2.y, w4.z, acc[1][2]);
      acc[1][3] = fmaf(a2.y, w4.w, acc[1][3]);
    }
    __syncthreads();
  }

  // ---- symmetric K-half exchange: write partial of row (1-h) ----
#pragma unroll
  for (int j = 0; j < 4; ++j) combX[h][j][t] = acc[1 - h][j];
  __syncthreads();

  // owned row r = h; combined = own partial + other half's partial
  float own[4];
#pragma unroll
  for (int j = 0; j < 4; ++j) own[j] = acc[h][j] + combX[1 ^ h][j][t];

  const float4 bv4 = *(const float4*)(bias + n0 + tx * 4);
  float4 o;
  o.x = __expf(2.0f * (own[0] + bv4.x));
  o.y = __expf(2.0f * (own[1] + bv4.y));
  o.z = __expf(2.0f * (own[2] + bv4.z));
  o.w = __expf(2.0f * (own[3] + bv4.w));
  if (is_pe) {
    // thread owns uq = n0/4+tx, t-row tg = t0 + ty*2 + h
    const int b = m0 >> 8, t0 = m0 & 255;
    const int uqg = (b << 6) + (n0 >> 2) + tx;
    const int tg = t0 + ty * 2;
    float* dst = EpeT2 + ((size_t)uqg << 10) + (tg << 2) + (h << 2);
    *(float4*)dst = o;
  } else {
    const int m = m0 + ty * 2 + h;  // global dec row (b*256+s)
    *(float4*)(Epd + ((size_t)m << 8) + n0 + tx * 4) = o;
  }
}

// K23: fused score+softmax+context, 512 threads (8 waves), grid 512 =
// (b, s-quad), XCD swizzle. Structure = R10 (best measured, 47.5us;
// R11's quad-denominator reverted: VGPR 68 > 64 occupancy step).
// Phase 1: u-quarter hq x t-pair {p, p+128}; 5 broadcast ds_read feed
// 64 FMA + 32 rcp. Partials via 16KB LDS.
// Softmax (R12): SPLIT across all 8 waves — waves 0-3 rows 0-1, waves
// 4-7 rows 2-3 (was: waves 0-3 doing all 4 rows, upper half idle).
// No-max form (validated R6-R11).
// Phase 2: 4 cols/thread x t-quarter, 24KB combine (R9 form).
__global__ __launch_bounds__(512) void score_ctx_kernel(
    const float* __restrict__ Epd, const float* __restrict__ EpeT2,
    const float* __restrict__ Vw, const float* __restrict__ enc,
    float* __restrict__ attn, float* __restrict__ ctx)
{
  __shared__ __align__(16) float eps[4 * 256];     // Epd rows (4KB)
  __shared__ __align__(16) float vws[256];         // Vw (1KB)
  __shared__ __align__(16) float comb[4][4][256];  // u-quarter partials (16KB)
  __shared__ __align__(16) float att[4][256];      // probs (4KB)
  __shared__ __align__(16) float ctx2[3][4][512];  // t-quarter partials (24KB)
  __shared__ float reds[4][4];

  const int blk0 = blockIdx.x;
  const int blk = ((blk0 & 7) << 6) | (blk0 >> 3);  // T1 XCD swizzle
  const int b = blk >> 6;
  const int s0 = (blk & 63) << 2;
  const int tid = threadIdx.x;

  // ---- stage Epd 4 rows (contiguous 4KB) + Vw (1KB) into LDS ----
  if (tid < 256) {
    ((float4*)eps)[tid] =
        ((const float4*)(Epd + (((size_t)((b << 8) + s0)) << 8)))[tid];
  } else if (tid < 320) {
    ((float4*)vws)[tid - 256] = ((const float4*)Vw)[tid - 256];
  }
  __syncthreads();

  // ---- Phase 1: u-quarter hq, t-pair {p, p+128} (R10 form) ----
  const int p = tid & 127;
  const int hq = tid >> 7;  // 0..3 (wave-uniform: 2 waves per quarter)
  const int qb = hq << 4;   // 16 q per quarter
  const float* __restrict__ epA =
      EpeT2 + ((size_t)b << 16) + ((size_t)qb << 10) + (p << 2);
  const float* __restrict__ epB = epA + (128 << 2);

  float accA[4] = {};  // rows, t = p
  float accB[4] = {};  // rows, t = p+128
  float4 ga = *(const float4*)epA;
  float4 gb = *(const float4*)epB;
#pragma unroll 4
  for (int q = 0; q < 16; ++q) {
    float4 gan, gbn;
    if (q + 1 < 16) {
      gan = *(const float4*)(epA + ((size_t)(q + 1) << 10));
      gbn = *(const float4*)(epB + ((size_t)(q + 1) << 10));
    }
    const int u4 = (qb + q) << 2;
    const float4 vw = *(const float4*)&vws[u4];
    const float4 er[4] = {*(const float4*)&eps[u4],
                          *(const float4*)&eps[256 + u4],
                          *(const float4*)&eps[512 + u4],
                          *(const float4*)&eps[768 + u4]};
#pragma unroll
    for (int r = 0; r < 4; ++r) {
      const float4 e = er[r];
      accA[r] = fmaf(vw.x, __builtin_amdgcn_rcpf(fmaf(e.x, ga.x, 1.0f)), accA[r]);
      accA[r] = fmaf(vw.y, __builtin_amdgcn_rcpf(fmaf(e.y, ga.y, 1.0f)), accA[r]);
      accA[r] = fmaf(vw.z, __builtin_amdgcn_rcpf(fmaf(e.z, ga.z, 1.0f)), accA[r]);
      accA[r] = fmaf(vw.w, __builtin_amdgcn_rcpf(fmaf(e.w, ga.w, 1.0f)), accA[r]);
      accB[r] = fmaf(vw.x, __builtin_amdgcn_rcpf(fmaf(e.x, gb.x, 1.0f)), accB[r]);
      accB[r] = fmaf(vw.y, __builtin_amdgcn_rcpf(fmaf(e.y, gb.y, 1.0f)), accB[r]);
      accB[r] = fmaf(vw.z, __builtin_amdgcn_rcpf(fmaf(e.z, gb.z, 1.0f)), accB[r]);
      accB[r] = fmaf(vw.w, __builtin_amdgcn_rcpf(fmaf(e.w, gb.w, 1.0f)), accB[r]);
    }
    ga = gan;
    gb = gbn;
  }

#pragma unroll
  for (int r = 0; r < 4; ++r) {
    comb[hq][r][p] = accA[r];
    comb[hq][r][p + 128] = accB[r];
  }
  __syncthreads();

  // ---- combine quarters + no-max softmax, SPLIT across all 8 waves ----
  // waves 0-3 (tid<256): rows 0,1 with t=tid; waves 4-7: rows 2,3, t=tid-256.
  const int t = tid & 255;
  const int rb = (tid < 256) ? 0 : 2;  // row base for this half
  const int wid = tid >> 6, lane = tid & 63;
  float e2[2];
#pragma unroll
  for (int i = 0; i < 2; ++i) {
    const int r = rb + i;
    const float v = (comb[0][r][t] + comb[1][r][t]) +
                    (comb[2][r][t] + comb[3][r][t]);
    e2[i] = __expf(-2.f * v);
    float s = e2[i];
#pragma unroll
    for (int off = 32; off; off >>= 1) s += __shfl_xor(s, off);
    if (lane == 0) reds[r][wid & 3] = s;
  }
  __syncthreads();
#pragma unroll
  for (int i = 0; i < 2; ++i) {
    const int r = rb + i;
    const float s = (reds[r][0] + reds[r][1]) + (reds[r][2] + reds[r][3]);
    const float pr = e2[i] * __builtin_amdgcn_rcpf(s);
    attn[(((size_t)((b << 8) + s0 + r)) << 8) + t] = pr;
    att[r][t] = pr;
  }
  __syncthreads();

  // ---- Phase 2: thread owns cols c4..c4+3, rows s0..s0+3, t-quarter tq.
  const int c4 = (tid & 127) << 2;
  const int tq = tid >> 7;  // 0..3
  const int tb = tq << 6;   // 64 t per quarter
  const float* __restrict__ encb = enc + ((size_t)b << 17) + c4;
  float4 acc0 = {0.f, 0.f, 0.f, 0.f};
  float4 acc1 = {0.f, 0.f, 0.f, 0.f};
  float4 acc2 = {0.f, 0.f, 0.f, 0.f};
  float4 acc3 = {0.f, 0.f, 0.f, 0.f};
#pragma unroll 2
  for (int t0 = tb; t0 < tb + 64; t0 += 4) {
    const float4 p0 = *(const float4*)&att[0][t0];
    const float4 p1 = *(const float4*)&att[1][t0];
    const float4 p2 = *(const float4*)&att[2][t0];
    const float4 p3 = *(const float4*)&att[3][t0];
    const float pv0[4] = {p0.x, p0.y, p0.z, p0.w};
    const float pv1[4] = {p1.x, p1.y, p1.z, p1.w};
    const float pv2[4] = {p2.x, p2.y, p2.z, p2.w};
    const float pv3[4] = {p3.x, p3.y, p3.z, p3.w};
#pragma unroll
    for (int i = 0; i < 4; ++i) {
      const float4 ev = *(const float4*)(encb + ((size_t)(t0 + i) << 9));
      acc0.x = fmaf(pv0[i], ev.x, acc0.x);
      acc0.y = fmaf(pv0[i], ev.y, acc0.y);
      acc0.z = fmaf(pv0[i], ev.z, acc0.z);
      acc0.w = fmaf(pv0[i], ev.w, acc0.w);
      acc1.x = fmaf(pv1[i], ev.x, acc1.x);
      acc1.y = fmaf(pv1[i], ev.y, acc1.y);
      acc1.z = fmaf(pv1[i], ev.z, acc1.z);
      acc1.w = fmaf(pv1[i], ev.w, acc1.w);
      acc2.x = fmaf(pv2[i], ev.x, acc2.x);
      acc2.y = fmaf(pv2[i], ev.y, acc2.y);
      acc2.z = fmaf(pv2[i], ev.z, acc2.z);
      acc2.w = fmaf(pv2[i], ev.w, acc2.w);
      acc3.x = fmaf(pv3[i], ev.x, acc3.x);
      acc3.y = fmaf(pv3[i], ev.y, acc3.y);
      acc3.z = fmaf(pv3[i], ev.z, acc3.z);
      acc3.w = fmaf(pv3[i], ev.w, acc3.w);
    }
  }
  if (tq != 0) {
    *(float4*)&ctx2[tq - 1][0][c4] = acc0;
    *(float4*)&ctx2[tq - 1][1][c4] = acc1;
    *(float4*)&ctx2[tq - 1][2][c4] = acc2;
    *(float4*)&ctx2[tq - 1][3][c4] = acc3;
  }
  __syncthreads();
  if (tq == 0) {
#pragma unroll
    for (int q = 0; q < 3; ++q) {
      const float4 q0 = *(const float4*)&ctx2[q][0][c4];
      const float4 q1 = *(const float4*)&ctx2[q][1][c4];
      const float4 q2 = *(const float4*)&ctx2[q][2][c4];
      const float4 q3 = *(const float4*)&ctx2[q][3][c4];
      acc0.x += q0.x; acc0.y += q0.y; acc0.z += q0.z; acc0.w += q0.w;
      acc1.x += q1.x; acc1.y += q1.y; acc1.z += q1.z; acc1.w += q1.w;
      acc2.x += q2.x; acc2.y += q2.y; acc2.z += q2.z; acc2.w += q2.w;
      acc3.x += q3.x; acc3.y += q3.y; acc3.z += q3.z; acc3.w += q3.w;
    }
    float* __restrict__ cb = ctx + (((size_t)((b << 8) + s0)) << 9) + c4;
    *(float4*)(cb + 0 * ED) = acc0;
    *(float4*)(cb + 1 * ED) = acc1;
    *(float4*)(cb + 2 * ED) = acc2;
    *(float4*)(cb + 3 * ED) = acc3;
  }
}

extern "C" void kernel_launch(void* const* d_in, const int* in_sizes, int n_in,
                              void* d_out, int out_size, void* d_ws, size_t ws_size,
                              hipStream_t stream) {
  const float* enc = (const float*)d_in[0];
  const float* dec = (const float*)d_in[1];
  const float* W1 = (const float*)d_in[2];
  const float* b1 = (const float*)d_in[3];
  const float* W2 = (const float*)d_in[4];
  const float* b2 = (const float*)d_in[5];
  const float* Vw = (const float*)d_in[6];
  // Vb cancels in softmax — unused.

  float* ctx = (float*)d_out;                          // (8,256,512)
  float* attn = (float*)d_out + (size_t)NB * TD * ED;  // (8,256,256)
  float* Epd = (float*)d_ws;                           // 512K floats
  float* EpeT2 = Epd + (size_t)NB * TD * DU;           // 512K floats

  proj_exp_kernel<<<dim3(512), dim3(512), 0, stream>>>(enc, dec, W1, b1, W2,
                                                       b2, Epd, EpeT2);
  score_ctx_kernel<<<dim3(512), dim3(512), 0, stream>>>(Epd, EpeT2, Vw, enc,
                                                        attn, ctx);
}

// Round 13
// 47.477 us; speedup vs baseline: 1.0668x; 1.0201x over previous
//
#include <hip/hip_runtime.h>

#define NB 8
#define TE 256
#define TD 256
#define ED 512
#define DU 256

// EpeT2 layout: [b][uq=u/4][t][ui=u%4]  (64 x 256 x 4 floats per b = 65536)

// K1: proj+exp, 32x64 tiles, 512 threads (8 waves): K-split (R5 form,
// best measured). 2 blocks/CU x 8 waves = 4 waves/SIMD.
__global__ __launch_bounds__(512) void proj_exp_kernel(
    const float* __restrict__ enc, const float* __restrict__ dec,
    const float* __restrict__ W1, const float* __restrict__ b1,
    const float* __restrict__ W2, const float* __restrict__ b2,
    float* __restrict__ Epd, float* __restrict__ EpeT2)
{
  __shared__ __align__(16) float As[2][32][34];
  __shared__ __align__(16) float Bs[2][32][64];
  __shared__ __align__(16) float comb[8][256];
  const int blk = blockIdx.x;
  const bool is_pe = blk < 256;
  const int sub = blk & 255;
  const int K = is_pe ? ED : DU;
  const int NTh = K >> 6;  // K-tiles per half (pe: 8, pd: 4)
  const float* __restrict__ A = is_pe ? enc : dec;
  const float* __restrict__ W = is_pe ? W1 : W2;
  const float* __restrict__ bias = is_pe ? b1 : b2;
  const int mt = sub >> 2, nt = sub & 3;
  const int m0 = mt * 32, n0 = nt * 64;
  const int tid = threadIdx.x;
  const int t = tid & 255;  // index within half
  const int h = tid >> 8;   // K-half
  const int k0base = h * (K >> 1);
  const int tx = t & 15, ty = t >> 4;
  const int at = t >> 3, ka = (t & 7) << 2;   // A: row, k-offset
  const int kb = t >> 4, jb = (t & 15) << 2;  // W: k-row, col-offset

  const float* __restrict__ Ap = A + (size_t)(m0 + at) * K + k0base + ka;
  const float* __restrict__ Wp = W + (size_t)(k0base + kb) * DU + n0 + jb;

  float acc[2][4] = {};
  float4 aV, wV0, wV1;

  auto loadr = [&](int k0) {
    aV = *(const float4*)(Ap + k0);
    wV0 = *(const float4*)(Wp + (size_t)k0 * DU);
    wV1 = *(const float4*)(Wp + (size_t)(k0 + 16) * DU);
  };

  loadr(0);
  for (int kt = 0; kt < NTh; ++kt) {
    As[h][ka + 0][at] = aV.x;
    As[h][ka + 1][at] = aV.y;
    As[h][ka + 2][at] = aV.z;
    As[h][ka + 3][at] = aV.w;
    *(float4*)&Bs[h][kb][jb] = wV0;
    *(float4*)&Bs[h][kb + 16][jb] = wV1;
    __syncthreads();
    if (kt + 1 < NTh) loadr((kt + 1) << 5);
#pragma unroll
    for (int kk = 0; kk < 32; ++kk) {
      const float2 a2 = *(const float2*)&As[h][kk][ty * 2];
      const float4 w4 = *(const float4*)&Bs[h][kk][tx * 4];
      acc[0][0] = fmaf(a2.x, w4.x, acc[0][0]);
      acc[0][1] = fmaf(a2.x, w4.y, acc[0][1]);
      acc[0][2] = fmaf(a2.x, w4.z, acc[0][2]);
      acc[0][3] = fmaf(a2.x, w4.w, acc[0][3]);
      acc[1][0] = fmaf(a2.y, w4.x, acc[1][0]);
      acc[1][1] = fmaf(a2.y, w4.y, acc[1][1]);
      acc[1][2] = fmaf(a2.y, w4.z, acc[1][2]);
      acc[1][3] = fmaf(a2.y, w4.w, acc[1][3]);
    }
    __syncthreads();
  }

  // ---- combine K-halves ----
  if (h == 1) {
#pragma unroll
    for (int r = 0; r < 2; ++r)
#pragma unroll
      for (int j = 0; j < 4; ++j) comb[r * 4 + j][t] = acc[r][j];
  }
  __syncthreads();
  if (h == 0) {
#pragma unroll
    for (int r = 0; r < 2; ++r)
#pragma unroll
      for (int j = 0; j < 4; ++j) acc[r][j] += comb[r * 4 + j][t];

    const float4 bv4 = *(const float4*)(bias + n0 + tx * 4);
    const float bvv[4] = {bv4.x, bv4.y, bv4.z, bv4.w};
    if (is_pe) {
      const int b = m0 >> 8, t0 = m0 & 255;
      const int uqg = (b << 6) + (n0 >> 2) + tx;
      const int tg = t0 + ty * 2;
      float* dst = EpeT2 + ((size_t)uqg << 10) + (tg << 2);
      float4 o0, o1;
      o0.x = __expf(2.0f * (acc[0][0] + bvv[0]));
      o0.y = __expf(2.0f * (acc[0][1] + bvv[1]));
      o0.z = __expf(2.0f * (acc[0][2] + bvv[2]));
      o0.w = __expf(2.0f * (acc[0][3] + bvv[3]));
      o1.x = __expf(2.0f * (acc[1][0] + bvv[0]));
      o1.y = __expf(2.0f * (acc[1][1] + bvv[1]));
      o1.z = __expf(2.0f * (acc[1][2] + bvv[2]));
      o1.w = __expf(2.0f * (acc[1][3] + bvv[3]));
      *(float4*)dst = o0;
      *(float4*)(dst + 4) = o1;
    } else {
#pragma unroll
      for (int r = 0; r < 2; ++r) {
        const int m = m0 + ty * 2 + r;
        float4 o;
        o.x = __expf(2.0f * (acc[r][0] + bvv[0]));
        o.y = __expf(2.0f * (acc[r][1] + bvv[1]));
        o.z = __expf(2.0f * (acc[r][2] + bvv[2]));
        o.w = __expf(2.0f * (acc[r][3] + bvv[3]));
        *(float4*)(Epd + ((size_t)m << 8) + n0 + tx * 4) = o;
      }
    }
  }
}

// K23: fused score+softmax+context, 512 threads (8 waves), grid 512 =
// (b, s-quad), XCD swizzle. R10 form — session best (47.5us).
// Phase 1: u-quarter hq x t-pair {p, p+128}; 5 broadcast ds_read_b128
// (vw, e0..e3) feed 64 FMA + 32 rcp (2x reuse). Partials via 16KB LDS.
// Softmax: no-max (|score| <= 2*sum|Vw| ~ 26, fp32-safe; validated
// R6-R12) on threads 0..255.
// Phase 2: 4 cols/thread x t-quarter; each att ds_read_b128 feeds 16 FMA
// (R9 lever, -6us); enc read once per block, float4-coalesced; t-quarter
// partials via 24KB LDS.
// Local-optimum ledger: occupancy 2x (R8) = 0; rcp-reduction (R6,R11) =
// regression (VALU-issue / VGPR>64 cliff); tail-split (R12) = neutral.
__global__ __launch_bounds__(512) void score_ctx_kernel(
    const float* __restrict__ Epd, const float* __restrict__ EpeT2,
    const float* __restrict__ Vw, const float* __restrict__ enc,
    float* __restrict__ attn, float* __restrict__ ctx)
{
  __shared__ __align__(16) float eps[4 * 256];     // Epd rows (4KB)
  __shared__ __align__(16) float vws[256];         // Vw (1KB)
  __shared__ __align__(16) float comb[4][4][256];  // u-quarter partials (16KB)
  __shared__ __align__(16) float att[4][256];      // probs (4KB)
  __shared__ __align__(16) float ctx2[3][4][512];  // t-quarter partials (24KB)
  __shared__ float reds[4][4];

  const int blk0 = blockIdx.x;
  const int blk = ((blk0 & 7) << 6) | (blk0 >> 3);  // T1 XCD swizzle
  const int b = blk >> 6;
  const int s0 = (blk & 63) << 2;
  const int tid = threadIdx.x;

  // ---- stage Epd 4 rows (contiguous 4KB) + Vw (1KB) into LDS ----
  if (tid < 256) {
    ((float4*)eps)[tid] =
        ((const float4*)(Epd + (((size_t)((b << 8) + s0)) << 8)))[tid];
  } else if (tid < 320) {
    ((float4*)vws)[tid - 256] = ((const float4*)Vw)[tid - 256];
  }
  __syncthreads();

  // ---- Phase 1: u-quarter hq, t-pair {p, p+128} ----
  const int p = tid & 127;
  const int hq = tid >> 7;  // 0..3 (wave-uniform: 2 waves per quarter)
  const int qb = hq << 4;   // 16 q per quarter
  const float* __restrict__ epA =
      EpeT2 + ((size_t)b << 16) + ((size_t)qb << 10) + (p << 2);
  const float* __restrict__ epB = epA + (128 << 2);

  float accA[4] = {};  // rows, t = p
  float accB[4] = {};  // rows, t = p+128
  float4 ga = *(const float4*)epA;
  float4 gb = *(const float4*)epB;
#pragma unroll 4
  for (int q = 0; q < 16; ++q) {
    float4 gan, gbn;
    if (q + 1 < 16) {
      gan = *(const float4*)(epA + ((size_t)(q + 1) << 10));
      gbn = *(const float4*)(epB + ((size_t)(q + 1) << 10));
    }
    const int u4 = (qb + q) << 2;
    const float4 vw = *(const float4*)&vws[u4];
    const float4 er[4] = {*(const float4*)&eps[u4],
                          *(const float4*)&eps[256 + u4],
                          *(const float4*)&eps[512 + u4],
                          *(const float4*)&eps[768 + u4]};
#pragma unroll
    for (int r = 0; r < 4; ++r) {
      const float4 e = er[r];
      accA[r] = fmaf(vw.x, __builtin_amdgcn_rcpf(fmaf(e.x, ga.x, 1.0f)), accA[r]);
      accA[r] = fmaf(vw.y, __builtin_amdgcn_rcpf(fmaf(e.y, ga.y, 1.0f)), accA[r]);
      accA[r] = fmaf(vw.z, __builtin_amdgcn_rcpf(fmaf(e.z, ga.z, 1.0f)), accA[r]);
      accA[r] = fmaf(vw.w, __builtin_amdgcn_rcpf(fmaf(e.w, ga.w, 1.0f)), accA[r]);
      accB[r] = fmaf(vw.x, __builtin_amdgcn_rcpf(fmaf(e.x, gb.x, 1.0f)), accB[r]);
      accB[r] = fmaf(vw.y, __builtin_amdgcn_rcpf(fmaf(e.y, gb.y, 1.0f)), accB[r]);
      accB[r] = fmaf(vw.z, __builtin_amdgcn_rcpf(fmaf(e.z, gb.z, 1.0f)), accB[r]);
      accB[r] = fmaf(vw.w, __builtin_amdgcn_rcpf(fmaf(e.w, gb.w, 1.0f)), accB[r]);
    }
    ga = gan;
    gb = gbn;
  }

#pragma unroll
  for (int r = 0; r < 4; ++r) {
    comb[hq][r][p] = accA[r];
    comb[hq][r][p + 128] = accB[r];
  }
  __syncthreads();

  // ---- combine quarters + no-max softmax on threads 0..255 ----
  const int wid = tid >> 6, lane = tid & 63;
  float e[4];
  if (tid < 256) {
    const int t = tid;
#pragma unroll
    for (int r = 0; r < 4; ++r) {
      const float v = (comb[0][r][t] + comb[1][r][t]) +
                      (comb[2][r][t] + comb[3][r][t]);
      e[r] = __expf(-2.f * v);
      float s = e[r];
#pragma unroll
      for (int off = 32; off; off >>= 1) s += __shfl_xor(s, off);
      if (lane == 0) reds[r][wid] = s;
    }
  }
  __syncthreads();
  if (tid < 256) {
    const int t = tid;
#pragma unroll
    for (int r = 0; r < 4; ++r) {
      const float s = (reds[r][0] + reds[r][1]) + (reds[r][2] + reds[r][3]);
      const float pr = e[r] * __builtin_amdgcn_rcpf(s);
      attn[(((size_t)((b << 8) + s0 + r)) << 8) + t] = pr;
      att[r][t] = pr;
    }
  }
  __syncthreads();

  // ---- Phase 2: thread owns cols c4..c4+3, rows s0..s0+3, t-quarter tq.
  const int c4 = (tid & 127) << 2;
  const int tq = tid >> 7;  // 0..3
  const int tb = tq << 6;   // 64 t per quarter
  const float* __restrict__ encb = enc + ((size_t)b << 17) + c4;
  float4 acc0 = {0.f, 0.f, 0.f, 0.f};
  float4 acc1 = {0.f, 0.f, 0.f, 0.f};
  float4 acc2 = {0.f, 0.f, 0.f, 0.f};
  float4 acc3 = {0.f, 0.f, 0.f, 0.f};
#pragma unroll 2
  for (int t0 = tb; t0 < tb + 64; t0 += 4) {
    const float4 p0 = *(const float4*)&att[0][t0];
    const float4 p1 = *(const float4*)&att[1][t0];
    const float4 p2 = *(const float4*)&att[2][t0];
    const float4 p3 = *(const float4*)&att[3][t0];
    const float pv0[4] = {p0.x, p0.y, p0.z, p0.w};
    const float pv1[4] = {p1.x, p1.y, p1.z, p1.w};
    const float pv2[4] = {p2.x, p2.y, p2.z, p2.w};
    const float pv3[4] = {p3.x, p3.y, p3.z, p3.w};
#pragma unroll
    for (int i = 0; i < 4; ++i) {
      const float4 ev = *(const float4*)(encb + ((size_t)(t0 + i) << 9));
      acc0.x = fmaf(pv0[i], ev.x, acc0.x);
      acc0.y = fmaf(pv0[i], ev.y, acc0.y);
      acc0.z = fmaf(pv0[i], ev.z, acc0.z);
      acc0.w = fmaf(pv0[i], ev.w, acc0.w);
      acc1.x = fmaf(pv1[i], ev.x, acc1.x);
      acc1.y = fmaf(pv1[i], ev.y, acc1.y);
      acc1.z = fmaf(pv1[i], ev.z, acc1.z);
      acc1.w = fmaf(pv1[i], ev.w, acc1.w);
      acc2.x = fmaf(pv2[i], ev.x, acc2.x);
      acc2.y = fmaf(pv2[i], ev.y, acc2.y);
      acc2.z = fmaf(pv2[i], ev.z, acc2.z);
      acc2.w = fmaf(pv2[i], ev.w, acc2.w);
      acc3.x = fmaf(pv3[i], ev.x, acc3.x);
      acc3.y = fmaf(pv3[i], ev.y, acc3.y);
      acc3.z = fmaf(pv3[i], ev.z, acc3.z);
      acc3.w = fmaf(pv3[i], ev.w, acc3.w);
    }
  }
  if (tq != 0) {
    *(float4*)&ctx2[tq - 1][0][c4] = acc0;
    *(float4*)&ctx2[tq - 1][1][c4] = acc1;
    *(float4*)&ctx2[tq - 1][2][c4] = acc2;
    *(float4*)&ctx2[tq - 1][3][c4] = acc3;
  }
  __syncthreads();
  if (tq == 0) {
#pragma unroll
    for (int q = 0; q < 3; ++q) {
      const float4 q0 = *(const float4*)&ctx2[q][0][c4];
      const float4 q1 = *(const float4*)&ctx2[q][1][c4];
      const float4 q2 = *(const float4*)&ctx2[q][2][c4];
      const float4 q3 = *(const float4*)&ctx2[q][3][c4];
      acc0.x += q0.x; acc0.y += q0.y; acc0.z += q0.z; acc0.w += q0.w;
      acc1.x += q1.x; acc1.y += q1.y; acc1.z += q1.z; acc1.w += q1.w;
      acc2.x += q2.x; acc2.y += q2.y; acc2.z += q2.z; acc2.w += q2.w;
      acc3.x += q3.x; acc3.y += q3.y; acc3.z += q3.z; acc3.w += q3.w;
    }
    float* __restrict__ cb = ctx + (((size_t)((b << 8) + s0)) << 9) + c4;
    *(float4*)(cb + 0 * ED) = acc0;
    *(float4*)(cb + 1 * ED) = acc1;
    *(float4*)(cb + 2 * ED) = acc2;
    *(float4*)(cb + 3 * ED) = acc3;
  }
}

extern "C" void kernel_launch(void* const* d_in, const int* in_sizes, int n_in,
                              void* d_out, int out_size, void* d_ws, size_t ws_size,
                              hipStream_t stream) {
  const float* enc = (const float*)d_in[0];
  const float* dec = (const float*)d_in[1];
  const float* W1 = (const float*)d_in[2];
  const float* b1 = (const float*)d_in[3];
  const float* W2 = (const float*)d_in[4];
  const float* b2 = (const float*)d_in[5];
  const float* Vw = (const float*)d_in[6];
  // Vb cancels in softmax — unused.

  float* ctx = (float*)d_out;                          // (8,256,512)
  float* attn = (float*)d_out + (size_t)NB * TD * ED;  // (8,256,256)
  float* Epd = (float*)d_ws;                           // 512K floats
  float* EpeT2 = Epd + (size_t)NB * TD * DU;           // 512K floats

  proj_exp_kernel<<<dim3(512), dim3(512), 0, stream>>>(enc, dec, W1, b1, W2,
                                                       b2, Epd, EpeT2);
  score_ctx_kernel<<<dim3(512), dim3(512), 0, stream>>>(Epd, EpeT2, Vw, enc,
                                                        attn, ctx);
}